// Round 3
// baseline (137.540 us; speedup 1.0000x reference)
//
#include <hip/hip_runtime.h>
#include <hip/hip_bf16.h>

#define N_NODES 100000
#define N_EDGES 1600000
#define K_DIM 128
#define N_DIM 128

typedef __attribute__((ext_vector_type(8))) short bf16x8;   // 8 bf16 = 4 VGPRs
typedef __attribute__((ext_vector_type(4))) float f32x4;    // MFMA 16x16 accumulator

__device__ inline unsigned short f2bf(float f) {
    __hip_bfloat16 b = __float2bfloat16(f);
    return __builtin_bit_cast(unsigned short, b);
}

// Mark nodes with >=1 incoming edge (col side). Handles both int32 edge data
// and int64-as-int32-pairs (high words of non-negative int64 node ids are 0).
__global__ void flag_kernel(const int* __restrict__ ei,
                            unsigned char* __restrict__ flag) {
    bool is64 = ((ei[1] | ei[3] | ei[5] | ei[7]) == 0);
    int e = blockIdx.x * blockDim.x + threadIdx.x;
    if (e < N_EDGES) {
        int col = is64 ? ei[2 * N_EDGES + 2 * e] : ei[N_EDGES + e];
        flag[col] = 1;  // same-value racing stores are fine
    }
}

// out[n,:] = flag[n] ? (x @ W)[n,:] : 0.
// Inputs fp32 (runtime-sniffed, bf16 fallback); MFMA bf16; OUTPUT STORED FP32
// (reference output dtype is float32 per harness contract; round-2 failure
// signature matched fp32-read-of-packed-bf16 exactly).
__launch_bounds__(256)
__global__ void gemm_mask_kernel(const void* __restrict__ xv,
                                 const void* __restrict__ wv,
                                 const unsigned char* __restrict__ flag,
                                 float* __restrict__ out) {
    // W staged column-major bf16: ldsW[n*136 + k]. 136*2B stride: 16B-aligned
    // for ds_read_b128; 272/4 % 32 = 4 -> worst 2-way bank alias (free).
    __shared__ __attribute__((aligned(16))) unsigned short ldsW[N_DIM * 136];
    __shared__ int s_isbf16;

    const int tid = threadIdx.x;

    // ---- dtype sniff: does the low short of x's words parse as an O(1) bf16?
    // bf16 data: exponent field p~0.999 in range; fp32 data (random mantissa
    // bits in that position): p~0.06.  64 samples, majority vote.
    if (tid < 64) {
        unsigned int v = ((const unsigned int*)xv)[tid];
        unsigned int ex = (v >> 7) & 0xFF;
        bool good = (ex >= 117) && (ex <= 131);   // |val| in [2^-10, 2^4]
        unsigned long long m = __ballot(good);
        if (tid == 0) s_isbf16 = (__popcll(m) > 32) ? 1 : 0;
    }
    __syncthreads();
    const bool isbf16 = (s_isbf16 != 0);

    // ---- stage 128x128 W into LDS (transpose to column-major, as bf16)
    if (isbf16) {
        const unsigned short* wu = (const unsigned short*)wv;
#pragma unroll
        for (int i = 0; i < 8; ++i) {
            int g = (i * 256 + tid) * 8;
            uint4 v = *(const uint4*)(wu + g);
            unsigned short tmp[8];
            *(uint4*)tmp = v;
            int k = g >> 7, n0 = g & 127;
#pragma unroll
            for (int j = 0; j < 8; ++j) ldsW[(n0 + j) * 136 + k] = tmp[j];
        }
    } else {
        const float* wf = (const float*)wv;
#pragma unroll
        for (int i = 0; i < 8; ++i) {
            int g = (i * 256 + tid) * 8;
            f32x4 a0 = *(const f32x4*)(wf + g);
            f32x4 a1 = *(const f32x4*)(wf + g + 4);
            int k = g >> 7, n0 = g & 127;
#pragma unroll
            for (int j = 0; j < 4; ++j) {
                ldsW[(n0 + j) * 136 + k]     = f2bf(a0[j]);
                ldsW[(n0 + 4 + j) * 136 + k] = f2bf(a1[j]);
            }
        }
    }
    __syncthreads();

    const int lane = tid & 63;
    const int wave = tid >> 6;
    const int m    = lane & 15;   // A row / B col / C col
    const int quad = lane >> 4;   // 0..3

    const long row0 = (long)blockIdx.x * 64 + wave * 16;
    long row  = row0 + m;
    long rowc = row < N_NODES ? row : (N_NODES - 1);  // clamp for safe loads

    f32x4 acc[8];
#pragma unroll
    for (int t = 0; t < 8; ++t) acc[t] = (f32x4){0.f, 0.f, 0.f, 0.f};

    if (isbf16) {
        const unsigned short* xu = (const unsigned short*)xv;
#pragma unroll
        for (int kk = 0; kk < 4; ++kk) {
            const int kbase = kk * 32 + quad * 8;
            bf16x8 afrag = *(const bf16x8*)(xu + rowc * K_DIM + kbase);
#pragma unroll
            for (int t = 0; t < 8; ++t) {
                bf16x8 bfrag = *(const bf16x8*)(ldsW + (t * 16 + m) * 136 + kbase);
                acc[t] = __builtin_amdgcn_mfma_f32_16x16x32_bf16(afrag, bfrag,
                                                                 acc[t], 0, 0, 0);
            }
        }
    } else {
        const float* xf = (const float*)xv;
#pragma unroll
        for (int kk = 0; kk < 4; ++kk) {
            const int kbase = kk * 32 + quad * 8;
            f32x4 a0 = *(const f32x4*)(xf + rowc * K_DIM + kbase);
            f32x4 a1 = *(const f32x4*)(xf + rowc * K_DIM + kbase + 4);
            bf16x8 afrag;
#pragma unroll
            for (int j = 0; j < 4; ++j) {
                afrag[j]     = (short)f2bf(a0[j]);
                afrag[4 + j] = (short)f2bf(a1[j]);
            }
#pragma unroll
            for (int t = 0; t < 8; ++t) {
                bf16x8 bfrag = *(const bf16x8*)(ldsW + (t * 16 + m) * 136 + kbase);
                acc[t] = __builtin_amdgcn_mfma_f32_16x16x32_bf16(afrag, bfrag,
                                                                 acc[t], 0, 0, 0);
            }
        }
    }

    // C/D layout: col = lane&15, row = quad*4 + reg
#pragma unroll
    for (int r = 0; r < 4; ++r) {
        long orow = row0 + quad * 4 + r;
        if (orow < N_NODES) {
            float f = flag[orow] ? 1.0f : 0.0f;
#pragma unroll
            for (int t = 0; t < 8; ++t) {
                out[orow * N_DIM + t * 16 + m] = acc[t][r] * f;
            }
        }
    }
}

extern "C" void kernel_launch(void* const* d_in, const int* in_sizes, int n_in,
                              void* d_out, int out_size, void* d_ws, size_t ws_size,
                              hipStream_t stream) {
    const void* x = d_in[0];
    const void* w = d_in[1];
    // d_in[2] (att) is mathematically irrelevant: normalized attention weights
    // sum to s/(s+1e-16) == 1 per segment in fp32, and the reference
    // aggregates h[col]*alpha into col, so out[n] = h[n] (or 0 if no in-edge).
    const int* ei = (const int*)d_in[3];
    float* out = (float*)d_out;

    unsigned char* flag = (unsigned char*)d_ws;  // N_NODES bytes of scratch

    hipMemsetAsync(flag, 0, N_NODES, stream);
    flag_kernel<<<(N_EDGES + 255) / 256, 256, 0, stream>>>(ei, flag);
    gemm_mask_kernel<<<(N_NODES + 63) / 64, 256, 0, stream>>>(x, w, flag, out);
}

// Round 4
// 136.640 us; speedup vs baseline: 1.0066x; 1.0066x over previous
//
#include <hip/hip_runtime.h>
#include <hip/hip_bf16.h>

#define N_NODES 100000
#define N_EDGES 1600000
#define K_DIM 128
#define N_DIM 128
#define BM_WORDS 3125   // ceil(100000/32)

typedef __attribute__((ext_vector_type(8))) short bf16x8;   // 8 bf16 = 4 VGPRs
typedef __attribute__((ext_vector_type(4))) float f32x4;    // MFMA accumulator

__device__ inline unsigned short f2bf(float f) {
    __hip_bfloat16 b = __float2bfloat16(f);
    return __builtin_bit_cast(unsigned short, b);
}

// Build a 100000-bit "has incoming edge" bitmask. LDS-privatized per block:
// 1.6M LDS atomics (banked, parallel per-CU) + <=3125 global atomicOr per
// block instead of 1.6M scattered global byte stores.
__global__ __launch_bounds__(256) void flag_kernel(const int* __restrict__ ei,
                                                   unsigned int* __restrict__ gbm) {
    __shared__ unsigned int lbm[BM_WORDS];
    for (int i = threadIdx.x; i < BM_WORDS; i += 256) lbm[i] = 0;
    __syncthreads();

    // int64-as-int32-pairs vs int32 sniff (high words of non-neg int64 are 0)
    bool is64 = ((ei[1] | ei[3] | ei[5] | ei[7]) == 0);
    const int per = N_EDGES / 256;                 // 6250, grid is 256 blocks
    const int base = blockIdx.x * per;
    for (int t = threadIdx.x; t < per; t += 256) {
        int e = base + t;
        int col = is64 ? ei[2 * N_EDGES + 2 * e] : ei[N_EDGES + e];
        atomicOr(&lbm[col >> 5], 1u << (col & 31));
    }
    __syncthreads();

    for (int i = threadIdx.x; i < BM_WORDS; i += 256) {
        unsigned int v = lbm[i];
        if (v) atomicOr(&gbm[i], v);
    }
}

// out[n,:] = hasedge[n] ? (x @ W)[n,:] : 0.  fp32 in (confirmed rounds 1-3),
// bf16 MFMA, fp32 accumulate/store.  256 rows per block (4 m-tiles per wave,
// 32 f32x4 accumulators); W staged to LDS ONCE per block, conflict-free.
__global__ __launch_bounds__(256, 2)
void gemm_mask_kernel(const float* __restrict__ xf,
                      const float* __restrict__ wf,
                      const unsigned int* __restrict__ gbm,
                      float* __restrict__ out) {
    // Column-major bf16 W: ldsW[n*136 + k]. Stride 136 shorts = 272 B
    // (16B-aligned for b128; word stride 68 -> banks advance by 4 per column).
    __shared__ __attribute__((aligned(16))) unsigned short ldsW[N_DIM * 136];

    const int tid = threadIdx.x;

    // Transpose-read staging: thread handles chunk c -> column n, k-run k0..k0+7.
    // Global reads: for fixed j, consecutive lanes read consecutive n -> fully
    // coalesced (L2/L3-hit; W is 64 KB).  LDS write: ds_write_b128 at word
    // 68*n + k0/2 -> lanes 0..7 start at banks 0,4,...,28, covering all 32
    // banks exactly 8x per wave = the conflict-free minimum.
#pragma unroll
    for (int i = 0; i < 8; ++i) {
        int c = i * 256 + tid;            // 0..2047
        int n = c & 127;
        int k0 = (c >> 7) << 3;           // 0,8,...,120
        unsigned short tmp[8];
#pragma unroll
        for (int j = 0; j < 8; ++j) tmp[j] = f2bf(wf[(k0 + j) * N_DIM + n]);
        *(uint4*)(ldsW + n * 136 + k0) = *(const uint4*)tmp;
    }
    __syncthreads();

    const int lane = tid & 63;
    const int wave = tid >> 6;
    const int m    = lane & 15;   // A row / B col / C col
    const int quad = lane >> 4;   // 0..3

    const int rb = blockIdx.x * 256 + wave * 64;   // wave's first row

    int rowc[4];
#pragma unroll
    for (int mt = 0; mt < 4; ++mt) {
        int r = rb + mt * 16 + m;
        rowc[mt] = r < N_NODES ? r : (N_NODES - 1);   // clamp: loads stay safe
    }

    f32x4 acc[4][8];
#pragma unroll
    for (int mt = 0; mt < 4; ++mt)
#pragma unroll
        for (int t = 0; t < 8; ++t) acc[mt][t] = (f32x4){0.f, 0.f, 0.f, 0.f};

#pragma unroll
    for (int kk = 0; kk < 4; ++kk) {
        const int kbase = kk * 32 + quad * 8;
        bf16x8 af[4];
#pragma unroll
        for (int mt = 0; mt < 4; ++mt) {
            f32x4 a0 = *(const f32x4*)(xf + rowc[mt] * K_DIM + kbase);
            f32x4 a1 = *(const f32x4*)(xf + rowc[mt] * K_DIM + kbase + 4);
            unsigned short t8[8];
#pragma unroll
            for (int j = 0; j < 4; ++j) {
                t8[j]     = f2bf(a0[j]);
                t8[4 + j] = f2bf(a1[j]);
            }
            af[mt] = *(const bf16x8*)t8;
        }
#pragma unroll
        for (int t = 0; t < 8; ++t) {
            bf16x8 bfrag = *(const bf16x8*)(ldsW + (t * 16 + m) * 136 + kbase);
#pragma unroll
            for (int mt = 0; mt < 4; ++mt)
                acc[mt][t] = __builtin_amdgcn_mfma_f32_16x16x32_bf16(
                    af[mt], bfrag, acc[mt][t], 0, 0, 0);
        }
    }

    // C/D layout: col = lane&15, row = quad*4 + reg
#pragma unroll
    for (int mt = 0; mt < 4; ++mt) {
#pragma unroll
        for (int r = 0; r < 4; ++r) {
            int orow = rb + mt * 16 + quad * 4 + r;
            if (orow < N_NODES) {
                float f = ((gbm[orow >> 5] >> (orow & 31)) & 1) ? 1.0f : 0.0f;
#pragma unroll
                for (int t = 0; t < 8; ++t)
                    out[orow * N_DIM + t * 16 + m] = acc[mt][t][r] * f;
            }
        }
    }
}

extern "C" void kernel_launch(void* const* d_in, const int* in_sizes, int n_in,
                              void* d_out, int out_size, void* d_ws, size_t ws_size,
                              hipStream_t stream) {
    const float* x = (const float*)d_in[0];
    const float* w = (const float*)d_in[1];
    // d_in[2] (att) is mathematically irrelevant: normalized attention weights
    // sum to s/(s+1e-16) == 1 per segment in fp32, and the reference
    // aggregates h[col]*alpha into col, so out[n] = h[n] (or 0 if no in-edge).
    const int* ei = (const int*)d_in[3];
    float* out = (float*)d_out;

    unsigned int* gbm = (unsigned int*)d_ws;   // 3125-word bitmask scratch

    hipMemsetAsync(gbm, 0, BM_WORDS * sizeof(unsigned int), stream);
    flag_kernel<<<256, 256, 0, stream>>>(ei, gbm);
    gemm_mask_kernel<<<(N_NODES + 255) / 256, 256, 0, stream>>>(x, w, gbm, out);
}

// Round 5
// 134.005 us; speedup vs baseline: 1.0264x; 1.0197x over previous
//
#include <hip/hip_runtime.h>
#include <hip/hip_bf16.h>

#define N_NODES 100000
#define N_EDGES 1600000
#define K_DIM 128
#define N_DIM 128
#define BM_WORDS 3125        // ceil(100000/32)
#define PART_STRIDE 3136     // per-block partial-mask stride, 64B-multiple
#define FLAG_BLOCKS 256
#define PART_OFF 4096        // word offset of partials in d_ws

typedef __attribute__((ext_vector_type(8))) short bf16x8;   // 8 bf16 = 4 VGPRs
typedef __attribute__((ext_vector_type(4))) float f32x4;    // MFMA accumulator

__device__ inline unsigned short f2bf(float f) {
    __hip_bfloat16 b = __float2bfloat16(f);
    return __builtin_bit_cast(unsigned short, b);
}

// Phase A: per-block private bitmask in LDS (LDS atomics only), written to a
// DISJOINT partial-mask region with plain coalesced stores. Zero global
// atomics -> no hot-line serialization at the LLC.
__global__ __launch_bounds__(256)
void flag_partial(const int* __restrict__ ei, unsigned int* __restrict__ parts) {
    __shared__ unsigned int lbm[BM_WORDS];
    for (int i = threadIdx.x; i < BM_WORDS; i += 256) lbm[i] = 0;
    __syncthreads();

    // int64-as-int32-pairs vs int32 sniff (high words of non-neg int64 are 0)
    bool is64 = ((ei[1] | ei[3] | ei[5] | ei[7]) == 0);
    const int base = blockIdx.x * (N_EDGES / FLAG_BLOCKS);   // 6250 edges/block
    if (is64) {
        // col array at words [2E, 4E), stride-2; uint4 = 2 edges. Alignment:
        // 4*(2E + 2*base) % 16 == 0 since base % 2 == 0.
        const uint4* p = (const uint4*)(ei + 2 * N_EDGES + 2 * base);
        for (int t = threadIdx.x; t < 3125; t += 256) {
            uint4 v = p[t];
            atomicOr(&lbm[v.x >> 5], 1u << (v.x & 31));
            atomicOr(&lbm[v.z >> 5], 1u << (v.z & 31));
        }
    } else {
        const uint2* p = (const uint2*)(ei + N_EDGES + base);  // base even -> 8B-aligned
        for (int t = threadIdx.x; t < 3125; t += 256) {
            uint2 v = p[t];
            atomicOr(&lbm[v.x >> 5], 1u << (v.x & 31));
            atomicOr(&lbm[v.y >> 5], 1u << (v.y & 31));
        }
    }
    __syncthreads();

    unsigned int* dst = parts + (size_t)blockIdx.x * PART_STRIDE;
    for (int i = threadIdx.x; i < BM_WORDS; i += 256) dst[i] = lbm[i];
}

// Phase B: gbm[i] = OR over 256 partials. Coalesced loads (lanes sweep i),
// plain stores, fully overwrites gbm (so no memset needed).
__global__ __launch_bounds__(256)
void flag_reduce(const unsigned int* __restrict__ parts,
                 unsigned int* __restrict__ gbm) {
    int i = blockIdx.x * 256 + threadIdx.x;
    if (i < BM_WORDS) {
        unsigned int v = 0;
#pragma unroll 8
        for (int b = 0; b < FLAG_BLOCKS; ++b)
            v |= parts[(size_t)b * PART_STRIDE + i];
        gbm[i] = v;
    }
}

// out[n,:] = hasedge[n] ? (x @ W)[n,:] : 0.  fp32 in (confirmed rounds 1-3),
// bf16 MFMA, fp32 accumulate/store.  256 rows per block (4 m-tiles per wave,
// 32 f32x4 accumulators); W staged to LDS once per block, conflict-free.
__global__ __launch_bounds__(256, 2)
void gemm_mask_kernel(const float* __restrict__ xf,
                      const float* __restrict__ wf,
                      const unsigned int* __restrict__ gbm,
                      float* __restrict__ out) {
    // Column-major bf16 W: ldsW[n*136 + k]. 136 shorts = 272 B stride:
    // 16B-aligned for b128; word stride 68 -> banks advance 4/column.
    __shared__ __attribute__((aligned(16))) unsigned short ldsW[N_DIM * 136];

    const int tid = threadIdx.x;

    // Transpose-read staging: coalesced global reads along n (W is 64 KB,
    // L2-resident), ds_write_b128 at word 68*n + k0/2 -> conflict-free.
#pragma unroll
    for (int i = 0; i < 8; ++i) {
        int c = i * 256 + tid;            // 0..2047
        int n = c & 127;
        int k0 = (c >> 7) << 3;           // 0,8,...,120
        unsigned short tmp[8];
#pragma unroll
        for (int j = 0; j < 8; ++j) tmp[j] = f2bf(wf[(k0 + j) * N_DIM + n]);
        *(uint4*)(ldsW + n * 136 + k0) = *(const uint4*)tmp;
    }
    __syncthreads();

    const int lane = tid & 63;
    const int wave = tid >> 6;
    const int m    = lane & 15;   // A row / B col / C col
    const int quad = lane >> 4;   // 0..3

    const int rb = blockIdx.x * 256 + wave * 64;   // wave's first row

    int rowc[4];
#pragma unroll
    for (int mt = 0; mt < 4; ++mt) {
        int r = rb + mt * 16 + m;
        rowc[mt] = r < N_NODES ? r : (N_NODES - 1);   // clamp: loads stay safe
    }

    f32x4 acc[4][8];
#pragma unroll
    for (int mt = 0; mt < 4; ++mt)
#pragma unroll
        for (int t = 0; t < 8; ++t) acc[mt][t] = (f32x4){0.f, 0.f, 0.f, 0.f};

#pragma unroll
    for (int kk = 0; kk < 4; ++kk) {
        const int kbase = kk * 32 + quad * 8;
        bf16x8 af[4];
#pragma unroll
        for (int mt = 0; mt < 4; ++mt) {
            f32x4 a0 = *(const f32x4*)(xf + rowc[mt] * K_DIM + kbase);
            f32x4 a1 = *(const f32x4*)(xf + rowc[mt] * K_DIM + kbase + 4);
            unsigned short t8[8];
#pragma unroll
            for (int j = 0; j < 4; ++j) {
                t8[j]     = f2bf(a0[j]);
                t8[4 + j] = f2bf(a1[j]);
            }
            af[mt] = *(const bf16x8*)t8;
        }
#pragma unroll
        for (int t = 0; t < 8; ++t) {
            bf16x8 bfrag = *(const bf16x8*)(ldsW + (t * 16 + m) * 136 + kbase);
#pragma unroll
            for (int mt = 0; mt < 4; ++mt)
                acc[mt][t] = __builtin_amdgcn_mfma_f32_16x16x32_bf16(
                    af[mt], bfrag, acc[mt][t], 0, 0, 0);
        }
    }

    // C/D layout: col = lane&15, row = quad*4 + reg
#pragma unroll
    for (int mt = 0; mt < 4; ++mt) {
#pragma unroll
        for (int r = 0; r < 4; ++r) {
            int orow = rb + mt * 16 + quad * 4 + r;
            if (orow < N_NODES) {
                float f = ((gbm[orow >> 5] >> (orow & 31)) & 1) ? 1.0f : 0.0f;
#pragma unroll
                for (int t = 0; t < 8; ++t)
                    out[orow * N_DIM + t * 16 + m] = acc[mt][t][r] * f;
            }
        }
    }
}

extern "C" void kernel_launch(void* const* d_in, const int* in_sizes, int n_in,
                              void* d_out, int out_size, void* d_ws, size_t ws_size,
                              hipStream_t stream) {
    const float* x = (const float*)d_in[0];
    const float* w = (const float*)d_in[1];
    // d_in[2] (att) is mathematically irrelevant: normalized attention weights
    // sum to s/(s+1e-16) == 1 per segment in fp32, and the reference
    // aggregates h[col]*alpha into col, so out[n] = h[n] (or 0 if no in-edge).
    const int* ei = (const int*)d_in[3];
    float* out = (float*)d_out;

    unsigned int* gbm   = (unsigned int*)d_ws;            // final bitmask
    unsigned int* parts = (unsigned int*)d_ws + PART_OFF; // 256 partial masks

    flag_partial<<<FLAG_BLOCKS, 256, 0, stream>>>(ei, parts);
    flag_reduce<<<(BM_WORDS + 255) / 256, 256, 0, stream>>>(parts, gbm);
    gemm_mask_kernel<<<(N_NODES + 255) / 256, 256, 0, stream>>>(x, w, gbm, out);
}